// Round 1
// baseline (440.696 us; speedup 1.0000x reference)
//
#include <hip/hip_runtime.h>

#define Bn 512
#define Kn 160
#define Hn 256
#define BK (Bn*Kn)
#define ALPHA 0.5f
#define MAX_SPAN 30
#define L_FGW 0.1f
#define L_SPAN 0.5f
#define L_CONS 0.3f
#define CH 80

__device__ __forceinline__ unsigned short f2b(float f) {
  unsigned int u = __float_as_uint(f);
  unsigned int r = (u + 0x7fffu + ((u >> 16) & 1u)) >> 16;  // RNE
  return (unsigned short)r;
}
__device__ __forceinline__ float b2f(unsigned short h) {
  return __uint_as_float(((unsigned int)h) << 16);
}

__global__ void zero_acc_k(float* __restrict__ acc) {
  if (threadIdx.x < 16) acc[threadIdx.x] = 0.f;
}

// ---- QA head logits: one wave per (emb,row); H=256 = 64 lanes x float4 ----
__global__ __launch_bounds__(256) void qa_logits_k(
    const float* __restrict__ en, const float* __restrict__ vi,
    const float* __restrict__ w_s, const float* __restrict__ b_s,
    const float* __restrict__ w_e, const float* __restrict__ b_e,
    float* __restrict__ wsl) {
  int row = blockIdx.x * 4 + (threadIdx.x >> 6);
  int lane = threadIdx.x & 63;
  bool isVi = row >= BK;
  int r = isVi ? row - BK : row;
  const float* emb = isVi ? vi : en;
  float4 v = *(const float4*)(emb + (size_t)r * Hn + lane * 4);
  float4 a = *(const float4*)(w_s + lane * 4);
  float4 c = *(const float4*)(w_e + lane * 4);
  float ds = v.x*a.x + v.y*a.y + v.z*a.z + v.w*a.w;
  float de = v.x*c.x + v.y*c.y + v.z*c.z + v.w*c.w;
  #pragma unroll
  for (int o = 32; o; o >>= 1) { ds += __shfl_xor(ds, o); de += __shfl_xor(de, o); }
  if (lane == 0) {
    size_t base = isVi ? (size_t)2 * BK : 0;
    wsl[base + r] = ds + b_s[0];
    wsl[base + BK + r] = de + b_e[0];
  }
}

// ---- per-batch gamma stats: p (row sums), q (col sums), w = sum(M*gamma) ----
__global__ __launch_bounds__(256) void batch_stats_k(
    const float* __restrict__ gam, const float* __restrict__ M,
    float* __restrict__ p_arr, float* __restrict__ q_arr, float* __restrict__ acc) {
  __shared__ float qsh[Kn];
  __shared__ float wsh[4];
  int b = blockIdx.x;
  int tid = threadIdx.x;
  int wid = tid >> 6, lane = tid & 63;
  for (int t = tid; t < Kn; t += 256) qsh[t] = 0.f;
  __syncthreads();
  const float* gb = gam + (size_t)b * Kn * Kn;
  const float* mb = M + (size_t)b * Kn * Kn;
  float q0 = 0.f, q1 = 0.f, q2 = 0.f, wloc = 0.f;
  for (int i = wid; i < Kn; i += 4) {
    const float* row = gb + (size_t)i * Kn;
    const float* mrow = mb + (size_t)i * Kn;
    float g0 = row[lane];
    float g1 = row[lane + 64];
    float g2v = (lane < 32) ? row[lane + 128] : 0.f;
    float m0 = mrow[lane];
    float m1 = mrow[lane + 64];
    float m2 = (lane < 32) ? mrow[lane + 128] : 0.f;
    q0 += g0; q1 += g1; q2 += g2v;
    wloc += m0 * g0 + m1 * g1 + m2 * g2v;
    float rs = g0 + g1 + g2v;
    #pragma unroll
    for (int o = 32; o; o >>= 1) rs += __shfl_xor(rs, o);
    if (lane == 0) p_arr[(size_t)b * Kn + i] = rs;
  }
  atomicAdd(&qsh[lane], q0);
  atomicAdd(&qsh[lane + 64], q1);
  if (lane < 32) atomicAdd(&qsh[lane + 128], q2);
  #pragma unroll
  for (int o = 32; o; o >>= 1) wloc += __shfl_xor(wloc, o);
  if (lane == 0) wsh[wid] = wloc;
  __syncthreads();
  if (tid < Kn) q_arr[(size_t)b * Kn + tid] = qsh[tid];
  if (tid == 0) atomicAdd(acc + 4, wsh[0] + wsh[1] + wsh[2] + wsh[3]);
}

// ---- per-batch logit losses: QA CE + consistency KL; one wave per batch ----
__global__ __launch_bounds__(64) void logit_losses_k(
    const float* __restrict__ wsl, const int* __restrict__ enst,
    const int* __restrict__ enen, float* __restrict__ lse_vs,
    float* __restrict__ lse_ve, float* __restrict__ acc) {
  int b = blockIdx.x;
  int lane = threadIdx.x;
  const float* es = wsl + (size_t)b * Kn;
  const float* ee = wsl + (size_t)BK + (size_t)b * Kn;
  const float* vs = wsl + (size_t)2 * BK + (size_t)b * Kn;
  const float* ve = wsl + (size_t)3 * BK + (size_t)b * Kn;
  float xes[3], xee[3], xvs[3], xve[3];
  #pragma unroll
  for (int j = 0; j < 3; ++j) {
    int idx = lane + 64 * j;
    bool val = idx < Kn;
    xes[j] = val ? es[idx] : -1e30f;
    xee[j] = val ? ee[idx] : -1e30f;
    xvs[j] = val ? vs[idx] : -1e30f;
    xve[j] = val ? ve[idx] : -1e30f;
  }
  auto wlse = [&](float x0, float x1, float x2) -> float {
    float m = fmaxf(fmaxf(x0, x1), x2);
    #pragma unroll
    for (int o = 32; o; o >>= 1) m = fmaxf(m, __shfl_xor(m, o));
    float s = expf(x0 - m) + expf(x1 - m) + expf(x2 - m);
    #pragma unroll
    for (int o = 32; o; o >>= 1) s += __shfl_xor(s, o);
    return m + logf(s);
  };
  float l_es = wlse(xes[0], xes[1], xes[2]);
  float l_ee = wlse(xee[0], xee[1], xee[2]);
  float l_vs = wlse(xvs[0], xvs[1], xvs[2]);
  float l_ve = wlse(xve[0], xve[1], xve[2]);
  float lT_es = wlse(xes[0]*0.5f, xes[1]*0.5f, xes[2]*0.5f);
  float lT_ee = wlse(xee[0]*0.5f, xee[1]*0.5f, xee[2]*0.5f);
  float lT_vs = wlse(xvs[0]*0.5f, xvs[1]*0.5f, xvs[2]*0.5f);
  float lT_ve = wlse(xve[0]*0.5f, xve[1]*0.5f, xve[2]*0.5f);
  float kls = 0.f, kle = 0.f;
  #pragma unroll
  for (int j = 0; j < 3; ++j) {
    int idx = lane + 64 * j;
    if (idx < Kn) {
      float aa = xes[j]*0.5f - lT_es;
      float bb = xvs[j]*0.5f - lT_vs;
      kls += expf(aa) * (aa - bb);
      float cc = xee[j]*0.5f - lT_ee;
      float dd = xve[j]*0.5f - lT_ve;
      kle += expf(cc) * (cc - dd);
    }
  }
  #pragma unroll
  for (int o = 32; o; o >>= 1) { kls += __shfl_xor(kls, o); kle += __shfl_xor(kle, o); }
  if (lane == 0) {
    int sl = min(max(enst[b], 0), Kn - 1);
    int el = min(max(enen[b], 0), Kn - 1);
    atomicAdd(acc + 0, l_es - es[sl]);
    atomicAdd(acc + 1, l_ee - ee[el]);
    atomicAdd(acc + 2, kls);
    atomicAdd(acc + 3, kle);
    lse_vs[b] = l_vs;
    lse_ve[b] = l_ve;
  }
}

// ---- span decode (pseudo labels) + masked span CE; one block per batch ----
__global__ __launch_bounds__(256) void span_k(
    const float* __restrict__ gam, const int* __restrict__ enst,
    const int* __restrict__ enen, const float* __restrict__ wsl,
    const float* __restrict__ lse_vs, const float* __restrict__ lse_ve,
    float* __restrict__ acc) {
  __shared__ float vsc[Kn];
  __shared__ float bv[256];
  __shared__ int bidx[256];
  int b = blockIdx.x, tid = threadIdx.x;
  int s0 = enst[b], e0 = enen[b];
  int s = min(max(s0, 0), Kn - 1);
  int e = max(s, min(max(e0, 0), Kn - 1));
  const float* gb = gam + (size_t)b * Kn * Kn;
  if (tid < Kn) {
    float a = 0.f;
    for (int i = s; i <= e; ++i) a += gb[(size_t)i * Kn + tid];
    vsc[tid] = a;
  }
  __syncthreads();
  float best = -1e30f;
  int bfl = 0x7fffffff;
  if (tid < Kn) {
    float vsi = vsc[tid];
    int hi = min(tid + MAX_SPAN, Kn - 1);
    for (int ei = tid; ei <= hi; ++ei) {
      float v = vsi + vsc[ei];
      if (v > best) { best = v; bfl = tid * Kn + ei; }  // first-max (np.argmax)
    }
  }
  bv[tid] = best; bidx[tid] = bfl;
  for (int st = 128; st > 0; st >>= 1) {
    __syncthreads();
    if (tid < st) {
      float v2 = bv[tid + st]; int i2 = bidx[tid + st];
      if (v2 > bv[tid] || (v2 == bv[tid] && i2 < bidx[tid])) { bv[tid] = v2; bidx[tid] = i2; }
    }
  }
  __syncthreads();
  if (tid == 0) {
    int fl = bidx[0];
    int ps = fl / Kn, pe = fl % Kn;
    if (s0 == 0 && e0 == 0) { ps = 0; pe = 0; }
    bool answerable = (s0 > 0) || (e0 > 0);
    const float* vs = wsl + (size_t)2 * BK + (size_t)b * Kn;
    const float* ve = wsl + (size_t)3 * BK + (size_t)b * Kn;
    float ce = 0.5f * ((lse_vs[b] - vs[ps]) + (lse_ve[b] - ve[pe]));
    if (answerable) { atomicAdd(acc + 8, ce); atomicAdd(acc + 9, 1.f); }
  }
}

// ---- fused FGW: gw3 = sum (D_en@g)∘(g@D_vi), plus gw1/gw2 off staging loads.
// block = (batch b, 80-row chunk). bf16 LDS staging, fp32 accumulate.
__global__ __launch_bounds__(256, 2) void fgw_k(
    const float* __restrict__ Den, const float* __restrict__ Dvi,
    const float* __restrict__ gam, const float* __restrict__ p_arr,
    const float* __restrict__ q_arr, float* __restrict__ acc) {
  __shared__ unsigned short DenT[Kn * 81];  // [k][ii] transposed, pad 81
  __shared__ unsigned short GamT[Kn * 81];  // [j][ii]
  __shared__ unsigned int gRow[16 * 80];    // packed bf16 pairs, gamma[k][:]
  __shared__ unsigned int dRow[16 * 80];    // D_vi[k][:]
  __shared__ float red[12];
  int bid = blockIdx.x;
  int b = bid & (Bn - 1);     // chunk = bid>>9: chunk pair 512 apart -> same XCD slot
  int chunk = bid >> 9;
  int i0 = chunk * CH;
  int tid = threadIdx.x;
  int ig = tid >> 4, lg = tid & 15;
  const float* den_b = Den + (size_t)b * Kn * Kn;
  const float* dvi_b = Dvi + (size_t)b * Kn * Kn;
  const float* gam_b = gam + (size_t)b * Kn * Kn;
  const float* pb = p_arr + (size_t)b * Kn;
  const float* qb = q_arr + (size_t)b * Kn;
  float gw1 = 0.f, gw2 = 0.f;
  for (int t = tid; t < CH * Kn; t += 256) {
    int ii = t / Kn;
    int k = t - ii * Kn;
    float v = den_b[(size_t)(i0 + ii) * Kn + k];
    gw1 += v * v * pb[i0 + ii] * pb[k];   // fp32, pre-rounding
    DenT[k * 81 + ii] = f2b(v);
    float g = gam_b[(size_t)(i0 + ii) * Kn + k];
    GamT[k * 81 + ii] = f2b(g);
  }
  float accA[5][10], accG[5][10];
  #pragma unroll
  for (int u = 0; u < 5; ++u)
    #pragma unroll
    for (int w = 0; w < 10; ++w) { accA[u][w] = 0.f; accG[u][w] = 0.f; }
  int ig5 = ig * 5, lg5 = lg * 5;
  for (int k0 = 0; k0 < Kn; k0 += 16) {
    __syncthreads();
    for (int t = tid; t < 16 * 80; t += 256) {
      int kk = t / 80;
      int l2 = t - kk * 80;
      float2 g2 = *(const float2*)(gam_b + (size_t)(k0 + kk) * Kn + l2 * 2);
      gRow[t] = (unsigned int)f2b(g2.x) | ((unsigned int)f2b(g2.y) << 16);
      float2 d2 = *(const float2*)(dvi_b + (size_t)(k0 + kk) * Kn + l2 * 2);
      dRow[t] = (unsigned int)f2b(d2.x) | ((unsigned int)f2b(d2.y) << 16);
      if (chunk == 0)
        gw2 += (d2.x * d2.x * qb[l2 * 2] + d2.y * d2.y * qb[l2 * 2 + 1]) * qb[k0 + kk];
    }
    __syncthreads();
    #pragma unroll 2
    for (int kk = 0; kk < 16; ++kk) {
      int k = k0 + kk;
      float a[5], gi[5];
      #pragma unroll
      for (int u = 0; u < 5; ++u) {
        a[u] = b2f(DenT[k * 81 + ig5 + u]);    // broadcast across lg
        gi[u] = b2f(GamT[k * 81 + ig5 + u]);
      }
      float g[10], d[10];
      #pragma unroll
      for (int v2 = 0; v2 < 5; ++v2) {
        unsigned int gg = gRow[kk * 80 + lg5 + v2];
        g[2 * v2] = __uint_as_float(gg << 16);
        g[2 * v2 + 1] = __uint_as_float(gg & 0xffff0000u);
        unsigned int dd = dRow[kk * 80 + lg5 + v2];
        d[2 * v2] = __uint_as_float(dd << 16);
        d[2 * v2 + 1] = __uint_as_float(dd & 0xffff0000u);
      }
      #pragma unroll
      for (int u = 0; u < 5; ++u)
        #pragma unroll
        for (int w = 0; w < 10; ++w) {
          accA[u][w] += a[u] * g[w];
          accG[u][w] += gi[u] * d[w];
        }
    }
  }
  float gw3 = 0.f;
  #pragma unroll
  for (int u = 0; u < 5; ++u)
    #pragma unroll
    for (int w = 0; w < 10; ++w) gw3 += accA[u][w] * accG[u][w];
  #pragma unroll
  for (int o = 32; o; o >>= 1) {
    gw1 += __shfl_xor(gw1, o);
    gw2 += __shfl_xor(gw2, o);
    gw3 += __shfl_xor(gw3, o);
  }
  int wid = tid >> 6, lane = tid & 63;
  if (lane == 0) { red[wid] = gw1; red[4 + wid] = gw2; red[8 + wid] = gw3; }
  __syncthreads();
  if (tid == 0) {
    atomicAdd(acc + 5, red[0] + red[1] + red[2] + red[3]);
    atomicAdd(acc + 6, red[4] + red[5] + red[6] + red[7]);
    atomicAdd(acc + 7, red[8] + red[9] + red[10] + red[11]);
  }
}

__global__ void finalize_k(const float* __restrict__ acc, float* __restrict__ out) {
  if (threadIdx.x == 0) {
    float ce_s = acc[0], ce_e = acc[1], kls = acc[2], kle = acc[3];
    float w = acc[4], gw1 = acc[5], gw2 = acc[6], gw3 = acc[7];
    float spn = acc[8], nans = acc[9];
    float l_qa = (ce_s + ce_e) / (2.f * Bn);
    float l_fgw = (ALPHA * (gw1 + gw2 - 2.f * gw3) + (1.f - ALPHA) * w) / Bn;
    float l_span = (nans > 0.f) ? spn / fmaxf(nans, 1.f) : 0.f;
    float l_cons = 2.f * (kls + kle) / Bn;  // T^2 * ((kls+kle)/B) / 2 with T=2
    float total = l_qa + L_FGW * l_fgw + L_SPAN * l_span + L_CONS * l_cons;
    out[0] = total; out[1] = l_qa; out[2] = l_fgw; out[3] = l_span; out[4] = l_cons;
  }
}

extern "C" void kernel_launch(void* const* d_in, const int* in_sizes, int n_in,
                              void* d_out, int out_size, void* d_ws, size_t ws_size,
                              hipStream_t stream) {
  const float* en  = (const float*)d_in[0];
  const float* vi  = (const float*)d_in[1];
  const float* gam = (const float*)d_in[2];
  const float* Den = (const float*)d_in[3];
  const float* Dvi = (const float*)d_in[4];
  const float* M   = (const float*)d_in[5];
  const int* enst  = (const int*)d_in[6];
  const int* enen  = (const int*)d_in[7];
  const float* w_s = (const float*)d_in[8];
  const float* b_s = (const float*)d_in[9];
  const float* w_e = (const float*)d_in[10];
  const float* b_e = (const float*)d_in[11];
  float* ws = (float*)d_ws;
  float* wsl = ws;                         // 4*BK logits: en_sl, en_el, vi_sl, vi_el
  float* lse_vs = ws + (size_t)4 * BK;     // B
  float* lse_ve = lse_vs + Bn;             // B
  float* p_arr = lse_ve + Bn;              // BK
  float* q_arr = p_arr + BK;               // BK
  float* acc = q_arr + BK;                 // 16 accumulators
  float* out = (float*)d_out;

  zero_acc_k<<<1, 64, 0, stream>>>(acc);
  qa_logits_k<<<(2 * BK) / 4, 256, 0, stream>>>(en, vi, w_s, b_s, w_e, b_e, wsl);
  batch_stats_k<<<Bn, 256, 0, stream>>>(gam, M, p_arr, q_arr, acc);
  logit_losses_k<<<Bn, 64, 0, stream>>>(wsl, enst, enen, lse_vs, lse_ve, acc);
  span_k<<<Bn, 256, 0, stream>>>(gam, enst, enen, wsl, lse_vs, lse_ve, acc);
  fgw_k<<<2 * Bn, 256, 0, stream>>>(Den, Dvi, gam, p_arr, q_arr, acc);
  finalize_k<<<1, 64, 0, stream>>>(acc, out);
}

// Round 2
// 233.249 us; speedup vs baseline: 1.8894x; 1.8894x over previous
//
#include <hip/hip_runtime.h>

#define Bn 512
#define Kn 160
#define Hn 256
#define BK (Bn*Kn)
#define ALPHA 0.5f
#define MAX_SPAN 30
#define L_FGW 0.1f
#define L_SPAN 0.5f
#define L_CONS 0.3f
#define KP 16
#define NP 10

typedef __bf16 bf16x8 __attribute__((ext_vector_type(8)));
typedef float f32x16 __attribute__((ext_vector_type(16)));
typedef unsigned short us8 __attribute__((ext_vector_type(8)));

__device__ __forceinline__ unsigned short f2b(float f) {
  unsigned int u = __float_as_uint(f);
  unsigned int r = (u + 0x7fffu + ((u >> 16) & 1u)) >> 16;  // RNE
  return (unsigned short)r;
}

__global__ void zero_acc_k(float* __restrict__ acc) {
  if (threadIdx.x < 16) acc[threadIdx.x] = 0.f;
}

// ---- QA head logits: one wave per (emb,row); H=256 = 64 lanes x float4 ----
__global__ __launch_bounds__(256) void qa_logits_k(
    const float* __restrict__ en, const float* __restrict__ vi,
    const float* __restrict__ w_s, const float* __restrict__ b_s,
    const float* __restrict__ w_e, const float* __restrict__ b_e,
    float* __restrict__ wsl) {
  int row = blockIdx.x * 4 + (threadIdx.x >> 6);
  int lane = threadIdx.x & 63;
  bool isVi = row >= BK;
  int r = isVi ? row - BK : row;
  const float* emb = isVi ? vi : en;
  float4 v = *(const float4*)(emb + (size_t)r * Hn + lane * 4);
  float4 a = *(const float4*)(w_s + lane * 4);
  float4 c = *(const float4*)(w_e + lane * 4);
  float ds = v.x*a.x + v.y*a.y + v.z*a.z + v.w*a.w;
  float de = v.x*c.x + v.y*c.y + v.z*c.z + v.w*c.w;
  #pragma unroll
  for (int o = 32; o; o >>= 1) { ds += __shfl_xor(ds, o); de += __shfl_xor(de, o); }
  if (lane == 0) {
    size_t base = isVi ? (size_t)2 * BK : 0;
    wsl[base + r] = ds + b_s[0];
    wsl[base + BK + r] = de + b_e[0];
  }
}

// ---- per-batch gamma stats: p (row sums), q (col sums), w = sum(M*gamma) ----
__global__ __launch_bounds__(256) void batch_stats_k(
    const float* __restrict__ gam, const float* __restrict__ M,
    float* __restrict__ p_arr, float* __restrict__ q_arr, float* __restrict__ acc) {
  __shared__ float qsh[Kn];
  __shared__ float wsh[4];
  int b = blockIdx.x;
  int tid = threadIdx.x;
  int wid = tid >> 6, lane = tid & 63;
  for (int t = tid; t < Kn; t += 256) qsh[t] = 0.f;
  __syncthreads();
  const float* gb = gam + (size_t)b * Kn * Kn;
  const float* mb = M + (size_t)b * Kn * Kn;
  float q0 = 0.f, q1 = 0.f, q2 = 0.f, wloc = 0.f;
  for (int i = wid; i < Kn; i += 4) {
    const float* row = gb + (size_t)i * Kn;
    const float* mrow = mb + (size_t)i * Kn;
    float g0 = row[lane];
    float g1 = row[lane + 64];
    float g2v = (lane < 32) ? row[lane + 128] : 0.f;
    float m0 = mrow[lane];
    float m1 = mrow[lane + 64];
    float m2 = (lane < 32) ? mrow[lane + 128] : 0.f;
    q0 += g0; q1 += g1; q2 += g2v;
    wloc += m0 * g0 + m1 * g1 + m2 * g2v;
    float rs = g0 + g1 + g2v;
    #pragma unroll
    for (int o = 32; o; o >>= 1) rs += __shfl_xor(rs, o);
    if (lane == 0) p_arr[(size_t)b * Kn + i] = rs;
  }
  atomicAdd(&qsh[lane], q0);
  atomicAdd(&qsh[lane + 64], q1);
  if (lane < 32) atomicAdd(&qsh[lane + 128], q2);
  #pragma unroll
  for (int o = 32; o; o >>= 1) wloc += __shfl_xor(wloc, o);
  if (lane == 0) wsh[wid] = wloc;
  __syncthreads();
  if (tid < Kn) q_arr[(size_t)b * Kn + tid] = qsh[tid];
  if (tid == 0) atomicAdd(acc + 4, wsh[0] + wsh[1] + wsh[2] + wsh[3]);
}

// ---- per-batch logit losses: QA CE + consistency KL; one wave per batch ----
__global__ __launch_bounds__(64) void logit_losses_k(
    const float* __restrict__ wsl, const int* __restrict__ enst,
    const int* __restrict__ enen, float* __restrict__ lse_vs,
    float* __restrict__ lse_ve, float* __restrict__ acc) {
  int b = blockIdx.x;
  int lane = threadIdx.x;
  const float* es = wsl + (size_t)b * Kn;
  const float* ee = wsl + (size_t)BK + (size_t)b * Kn;
  const float* vs = wsl + (size_t)2 * BK + (size_t)b * Kn;
  const float* ve = wsl + (size_t)3 * BK + (size_t)b * Kn;
  float xes[3], xee[3], xvs[3], xve[3];
  #pragma unroll
  for (int j = 0; j < 3; ++j) {
    int idx = lane + 64 * j;
    bool val = idx < Kn;
    xes[j] = val ? es[idx] : -1e30f;
    xee[j] = val ? ee[idx] : -1e30f;
    xvs[j] = val ? vs[idx] : -1e30f;
    xve[j] = val ? ve[idx] : -1e30f;
  }
  auto wlse = [&](float x0, float x1, float x2) -> float {
    float m = fmaxf(fmaxf(x0, x1), x2);
    #pragma unroll
    for (int o = 32; o; o >>= 1) m = fmaxf(m, __shfl_xor(m, o));
    float s = expf(x0 - m) + expf(x1 - m) + expf(x2 - m);
    #pragma unroll
    for (int o = 32; o; o >>= 1) s += __shfl_xor(s, o);
    return m + logf(s);
  };
  float l_es = wlse(xes[0], xes[1], xes[2]);
  float l_ee = wlse(xee[0], xee[1], xee[2]);
  float l_vs = wlse(xvs[0], xvs[1], xvs[2]);
  float l_ve = wlse(xve[0], xve[1], xve[2]);
  float lT_es = wlse(xes[0]*0.5f, xes[1]*0.5f, xes[2]*0.5f);
  float lT_ee = wlse(xee[0]*0.5f, xee[1]*0.5f, xee[2]*0.5f);
  float lT_vs = wlse(xvs[0]*0.5f, xvs[1]*0.5f, xvs[2]*0.5f);
  float lT_ve = wlse(xve[0]*0.5f, xve[1]*0.5f, xve[2]*0.5f);
  float kls = 0.f, kle = 0.f;
  #pragma unroll
  for (int j = 0; j < 3; ++j) {
    int idx = lane + 64 * j;
    if (idx < Kn) {
      float aa = xes[j]*0.5f - lT_es;
      float bb = xvs[j]*0.5f - lT_vs;
      kls += expf(aa) * (aa - bb);
      float cc = xee[j]*0.5f - lT_ee;
      float dd = xve[j]*0.5f - lT_ve;
      kle += expf(cc) * (cc - dd);
    }
  }
  #pragma unroll
  for (int o = 32; o; o >>= 1) { kls += __shfl_xor(kls, o); kle += __shfl_xor(kle, o); }
  if (lane == 0) {
    int sl = min(max(enst[b], 0), Kn - 1);
    int el = min(max(enen[b], 0), Kn - 1);
    atomicAdd(acc + 0, l_es - es[sl]);
    atomicAdd(acc + 1, l_ee - ee[el]);
    atomicAdd(acc + 2, kls);
    atomicAdd(acc + 3, kle);
    lse_vs[b] = l_vs;
    lse_ve[b] = l_ve;
  }
}

// ---- span decode (pseudo labels) + masked span CE; one block per batch ----
__global__ __launch_bounds__(256) void span_k(
    const float* __restrict__ gam, const int* __restrict__ enst,
    const int* __restrict__ enen, const float* __restrict__ wsl,
    const float* __restrict__ lse_vs, const float* __restrict__ lse_ve,
    float* __restrict__ acc) {
  __shared__ float vsc[Kn];
  __shared__ float bv[256];
  __shared__ int bidx[256];
  int b = blockIdx.x, tid = threadIdx.x;
  int s0 = enst[b], e0 = enen[b];
  int s = min(max(s0, 0), Kn - 1);
  int e = max(s, min(max(e0, 0), Kn - 1));
  const float* gb = gam + (size_t)b * Kn * Kn;
  if (tid < Kn) {
    float a = 0.f;
    for (int i = s; i <= e; ++i) a += gb[(size_t)i * Kn + tid];
    vsc[tid] = a;
  }
  __syncthreads();
  float best = -1e30f;
  int bfl = 0x7fffffff;
  if (tid < Kn) {
    float vsi = vsc[tid];
    int hi = min(tid + MAX_SPAN, Kn - 1);
    for (int ei = tid; ei <= hi; ++ei) {
      float v = vsi + vsc[ei];
      if (v > best) { best = v; bfl = tid * Kn + ei; }  // first-max (np.argmax)
    }
  }
  bv[tid] = best; bidx[tid] = bfl;
  for (int st = 128; st > 0; st >>= 1) {
    __syncthreads();
    if (tid < st) {
      float v2 = bv[tid + st]; int i2 = bidx[tid + st];
      if (v2 > bv[tid] || (v2 == bv[tid] && i2 < bidx[tid])) { bv[tid] = v2; bidx[tid] = i2; }
    }
  }
  __syncthreads();
  if (tid == 0) {
    int fl = bidx[0];
    int ps = fl / Kn, pe = fl % Kn;
    if (s0 == 0 && e0 == 0) { ps = 0; pe = 0; }
    bool answerable = (s0 > 0) || (e0 > 0);
    const float* vs = wsl + (size_t)2 * BK + (size_t)b * Kn;
    const float* ve = wsl + (size_t)3 * BK + (size_t)b * Kn;
    float ce = 0.5f * ((lse_vs[b] - vs[ps]) + (lse_ve[b] - ve[pe]));
    if (answerable) { atomicAdd(acc + 8, ce); atomicAdd(acc + 9, 1.f); }
  }
}

// ---- MFMA FGW: gw3 = sum (D_en@g) o (g@D_vi) via Y@X^T swap-trick.
// One block per batch, 8 waves, 25 tiles of 32x32, K-paneled (16) dbuf LDS.
// All operands staged as row-fragments [chunk][row][8] bf16 -> conflict-free
// ds_read_b128. gw1/gw2 fused into staging (each element read once).
__global__ __launch_bounds__(512, 2) void fgw_k(
    const float* __restrict__ Den, const float* __restrict__ Dvi,
    const float* __restrict__ gam, const float* __restrict__ p_arr,
    const float* __restrict__ q_arr, float* __restrict__ acc) {
  __shared__ __align__(16) unsigned short sDen[2][2][Kn][8];  // D_en rows
  __shared__ __align__(16) unsigned short sG  [2][2][Kn][8];  // gamma rows
  __shared__ __align__(16) unsigned short sGT [2][2][Kn][8];  // gamma^T rows
  __shared__ __align__(16) unsigned short sVT [2][2][Kn][8];  // D_vi^T rows
  __shared__ float pq[2 * Kn];
  __shared__ float red[24];
  int b = blockIdx.x;
  int tid = threadIdx.x;
  int wid = tid >> 6, lane = tid & 63;
  const float* den_b = Den + (size_t)b * Kn * Kn;
  const float* dvi_b = Dvi + (size_t)b * Kn * Kn;
  const float* gam_b = gam + (size_t)b * Kn * Kn;
  if (tid < 2 * Kn)
    pq[tid] = (tid < Kn) ? p_arr[(size_t)b * Kn + tid]
                         : q_arr[(size_t)b * Kn + (tid - Kn)];
  __syncthreads();
  float gw1 = 0.f, gw2 = 0.f;

  auto stage = [&](int p, int db) {
    int k0 = p * KP;
    for (int tau = tid; tau < 4 * 2 * Kn; tau += 512) {
      int bufid = tau / (2 * Kn);
      int f = tau - bufid * (2 * Kn);
      int c = (f >= Kn) ? 1 : 0;
      int r = f - c * Kn;
      int kb = k0 + c * 8;
      us8 w;
      if (bufid == 0) {            // D_en rows, fused gw1
        const float* src = den_b + (size_t)r * Kn + kb;
        float pi = pq[r];
        #pragma unroll
        for (int e = 0; e < 8; ++e) {
          float v = src[e];
          gw1 += v * v * pi * pq[kb + e];
          w[e] = f2b(v);
        }
        *(us8*)&sDen[db][c][r][0] = w;
      } else if (bufid == 1) {     // gamma rows
        const float* src = gam_b + (size_t)r * Kn + kb;
        #pragma unroll
        for (int e = 0; e < 8; ++e) w[e] = f2b(src[e]);
        *(us8*)&sG[db][c][r][0] = w;
      } else if (bufid == 2) {     // gamma^T rows (r = column j of gamma)
        #pragma unroll
        for (int e = 0; e < 8; ++e) w[e] = f2b(gam_b[(size_t)(kb + e) * Kn + r]);
        *(us8*)&sGT[db][c][r][0] = w;
      } else {                     // D_vi^T rows, fused gw2
        float qj = pq[Kn + r];
        #pragma unroll
        for (int e = 0; e < 8; ++e) {
          float v = dvi_b[(size_t)(kb + e) * Kn + r];
          gw2 += v * v * pq[Kn + kb + e] * qj;
          w[e] = f2b(v);
        }
        *(us8*)&sVT[db][c][r][0] = w;
      }
    }
  };

  f32x16 acc1[4] = {};
  f32x16 acc2[4] = {};
  stage(0, 0);
  __syncthreads();
  for (int p = 0; p < NP; ++p) {
    int cur = p & 1;
    if (p < NP - 1) stage(p + 1, cur ^ 1);
    int ra = lane & 31;
    int c = lane >> 5;
    #pragma unroll
    for (int n = 0; n < 4; ++n) {
      int t = wid + n * 8;
      if (t < 25) {
        int ti = t / 5, tj = t - (t / 5) * 5;
        int rowa = ti * 32 + ra;
        int rowb = tj * 32 + ra;
        bf16x8 a1 = *(const bf16x8*)&sDen[cur][c][rowa][0];
        bf16x8 b1 = *(const bf16x8*)&sGT[cur][c][rowb][0];
        bf16x8 a2 = *(const bf16x8*)&sG[cur][c][rowa][0];
        bf16x8 b2 = *(const bf16x8*)&sVT[cur][c][rowb][0];
        acc1[n] = __builtin_amdgcn_mfma_f32_32x32x16_bf16(a1, b1, acc1[n], 0, 0, 0);
        acc2[n] = __builtin_amdgcn_mfma_f32_32x32x16_bf16(a2, b2, acc2[n], 0, 0, 0);
      }
    }
    __syncthreads();
  }
  float g3 = 0.f;
  #pragma unroll
  for (int n = 0; n < 4; ++n) {
    int t = wid + n * 8;
    if (t < 25) {
      #pragma unroll
      for (int r = 0; r < 16; ++r) g3 += acc1[n][r] * acc2[n][r];
    }
  }
  #pragma unroll
  for (int o = 32; o; o >>= 1) {
    gw1 += __shfl_xor(gw1, o);
    gw2 += __shfl_xor(gw2, o);
    g3 += __shfl_xor(g3, o);
  }
  if (lane == 0) { red[wid] = gw1; red[8 + wid] = gw2; red[16 + wid] = g3; }
  __syncthreads();
  if (tid == 0) {
    float s1 = 0.f, s2 = 0.f, s3 = 0.f;
    #pragma unroll
    for (int i = 0; i < 8; ++i) { s1 += red[i]; s2 += red[8 + i]; s3 += red[16 + i]; }
    atomicAdd(acc + 5, s1);
    atomicAdd(acc + 6, s2);
    atomicAdd(acc + 7, s3);
  }
}

__global__ void finalize_k(const float* __restrict__ acc, float* __restrict__ out) {
  if (threadIdx.x == 0) {
    float ce_s = acc[0], ce_e = acc[1], kls = acc[2], kle = acc[3];
    float w = acc[4], gw1 = acc[5], gw2 = acc[6], gw3 = acc[7];
    float spn = acc[8], nans = acc[9];
    float l_qa = (ce_s + ce_e) / (2.f * Bn);
    float l_fgw = (ALPHA * (gw1 + gw2 - 2.f * gw3) + (1.f - ALPHA) * w) / Bn;
    float l_span = (nans > 0.f) ? spn / fmaxf(nans, 1.f) : 0.f;
    float l_cons = 2.f * (kls + kle) / Bn;  // T^2 * ((kls+kle)/B) / 2 with T=2
    float total = l_qa + L_FGW * l_fgw + L_SPAN * l_span + L_CONS * l_cons;
    out[0] = total; out[1] = l_qa; out[2] = l_fgw; out[3] = l_span; out[4] = l_cons;
  }
}

extern "C" void kernel_launch(void* const* d_in, const int* in_sizes, int n_in,
                              void* d_out, int out_size, void* d_ws, size_t ws_size,
                              hipStream_t stream) {
  const float* en  = (const float*)d_in[0];
  const float* vi  = (const float*)d_in[1];
  const float* gam = (const float*)d_in[2];
  const float* Den = (const float*)d_in[3];
  const float* Dvi = (const float*)d_in[4];
  const float* M   = (const float*)d_in[5];
  const int* enst  = (const int*)d_in[6];
  const int* enen  = (const int*)d_in[7];
  const float* w_s = (const float*)d_in[8];
  const float* b_s = (const float*)d_in[9];
  const float* w_e = (const float*)d_in[10];
  const float* b_e = (const float*)d_in[11];
  float* ws = (float*)d_ws;
  float* wsl = ws;                         // 4*BK logits: en_sl, en_el, vi_sl, vi_el
  float* lse_vs = ws + (size_t)4 * BK;     // B
  float* lse_ve = lse_vs + Bn;             // B
  float* p_arr = lse_ve + Bn;              // BK
  float* q_arr = p_arr + BK;               // BK
  float* acc = q_arr + BK;                 // 16 accumulators
  float* out = (float*)d_out;

  zero_acc_k<<<1, 64, 0, stream>>>(acc);
  qa_logits_k<<<(2 * BK) / 4, 256, 0, stream>>>(en, vi, w_s, b_s, w_e, b_e, wsl);
  batch_stats_k<<<Bn, 256, 0, stream>>>(gam, M, p_arr, q_arr, acc);
  logit_losses_k<<<Bn, 64, 0, stream>>>(wsl, enst, enen, lse_vs, lse_ve, acc);
  span_k<<<Bn, 256, 0, stream>>>(gam, enst, enen, wsl, lse_vs, lse_ve, acc);
  fgw_k<<<Bn, 512, 0, stream>>>(Den, Dvi, gam, p_arr, q_arr, acc);
  finalize_k<<<1, 64, 0, stream>>>(acc, out);
}

// Round 3
// 226.450 us; speedup vs baseline: 1.9461x; 1.0300x over previous
//
#include <hip/hip_runtime.h>

#define Bn 512
#define Kn 160
#define Hn 256
#define BK (Bn*Kn)
#define ALPHA 0.5f
#define MAX_SPAN 30
#define L_FGW 0.1f
#define L_SPAN 0.5f
#define L_CONS 0.3f
#define KP 16
#define NP 10

typedef __bf16 bf16x8 __attribute__((ext_vector_type(8)));
typedef float f32x16 __attribute__((ext_vector_type(16)));

// ---- QA head logits: one wave per (emb,row); H=256 = 64 lanes x float4 ----
// Block 0 also zeroes the scalar accumulator slab (consumed only by later kernels).
__global__ __launch_bounds__(256) void qa_logits_k(
    const float* __restrict__ en, const float* __restrict__ vi,
    const float* __restrict__ w_s, const float* __restrict__ b_s,
    const float* __restrict__ w_e, const float* __restrict__ b_e,
    float* __restrict__ wsl, float* __restrict__ acc) {
  if (blockIdx.x == 0 && threadIdx.x < 16) acc[threadIdx.x] = 0.f;
  int row = blockIdx.x * 4 + (threadIdx.x >> 6);
  int lane = threadIdx.x & 63;
  bool isVi = row >= BK;
  int r = isVi ? row - BK : row;
  const float* emb = isVi ? vi : en;
  float4 v = *(const float4*)(emb + (size_t)r * Hn + lane * 4);
  float4 a = *(const float4*)(w_s + lane * 4);
  float4 c = *(const float4*)(w_e + lane * 4);
  float ds = v.x*a.x + v.y*a.y + v.z*a.z + v.w*a.w;
  float de = v.x*c.x + v.y*c.y + v.z*c.z + v.w*c.w;
  #pragma unroll
  for (int o = 32; o; o >>= 1) { ds += __shfl_xor(ds, o); de += __shfl_xor(de, o); }
  if (lane == 0) {
    size_t base = isVi ? (size_t)2 * BK : 0;
    wsl[base + r] = ds + b_s[0];
    wsl[base + BK + r] = de + b_e[0];
  }
}

// ---- fused per-batch gamma stats + span decode: p, q, w, (ps,pe) ----
// One gamma pass (plus M): row sums -> p, col sums -> q (LDS), w = sum(M*g),
// vi_score accumulated for rows in [s,e]; then argmax span decode in LDS.
__global__ __launch_bounds__(256) void stats_span_k(
    const float* __restrict__ gam, const float* __restrict__ M,
    const int* __restrict__ enst, const int* __restrict__ enen,
    float* __restrict__ p_arr, float* __restrict__ q_arr,
    int* __restrict__ ps_arr, int* __restrict__ pe_arr,
    float* __restrict__ acc) {
  __shared__ float qsh[Kn];
  __shared__ float vsc[Kn];
  __shared__ float wsh[4];
  __shared__ float bv[256];
  __shared__ int bidx[256];
  int b = blockIdx.x;
  int tid = threadIdx.x;
  int wid = tid >> 6, lane = tid & 63;
  for (int t = tid; t < Kn; t += 256) { qsh[t] = 0.f; vsc[t] = 0.f; }
  __syncthreads();
  int s0 = enst[b], e0 = enen[b];
  int s = min(max(s0, 0), Kn - 1);
  int e = max(s, min(max(e0, 0), Kn - 1));
  const float* gb = gam + (size_t)b * Kn * Kn;
  const float* mb = M + (size_t)b * Kn * Kn;
  float q0 = 0.f, q1 = 0.f, q2 = 0.f, wloc = 0.f;
  for (int i = wid; i < Kn; i += 4) {
    const float* row = gb + (size_t)i * Kn;
    const float* mrow = mb + (size_t)i * Kn;
    float g0 = row[lane];
    float g1 = row[lane + 64];
    float g2v = (lane < 32) ? row[lane + 128] : 0.f;
    float m0 = mrow[lane];
    float m1 = mrow[lane + 64];
    float m2 = (lane < 32) ? mrow[lane + 128] : 0.f;
    q0 += g0; q1 += g1; q2 += g2v;
    wloc += m0 * g0 + m1 * g1 + m2 * g2v;
    float rs = g0 + g1 + g2v;
    #pragma unroll
    for (int o = 32; o; o >>= 1) rs += __shfl_xor(rs, o);
    if (lane == 0) p_arr[(size_t)b * Kn + i] = rs;
    if (i >= s && i <= e) {
      atomicAdd(&vsc[lane], g0);
      atomicAdd(&vsc[lane + 64], g1);
      if (lane < 32) atomicAdd(&vsc[lane + 128], g2v);
    }
  }
  atomicAdd(&qsh[lane], q0);
  atomicAdd(&qsh[lane + 64], q1);
  if (lane < 32) atomicAdd(&qsh[lane + 128], q2);
  #pragma unroll
  for (int o = 32; o; o >>= 1) wloc += __shfl_xor(wloc, o);
  if (lane == 0) wsh[wid] = wloc;
  __syncthreads();
  if (tid < Kn) q_arr[(size_t)b * Kn + tid] = qsh[tid];
  if (tid == 0) atomicAdd(acc + 4, wsh[0] + wsh[1] + wsh[2] + wsh[3]);
  // ---- span decode from vsc ----
  float best = -1e30f;
  int bfl = 0x7fffffff;
  if (tid < Kn) {
    float vsi = vsc[tid];
    int hi = min(tid + MAX_SPAN, Kn - 1);
    for (int ei = tid; ei <= hi; ++ei) {
      float v = vsi + vsc[ei];
      if (v > best) { best = v; bfl = tid * Kn + ei; }  // first-max (np.argmax)
    }
  }
  bv[tid] = best; bidx[tid] = bfl;
  for (int st = 128; st > 0; st >>= 1) {
    __syncthreads();
    if (tid < st) {
      float v2 = bv[tid + st]; int i2 = bidx[tid + st];
      if (v2 > bv[tid] || (v2 == bv[tid] && i2 < bidx[tid])) { bv[tid] = v2; bidx[tid] = i2; }
    }
  }
  __syncthreads();
  if (tid == 0) {
    int fl = bidx[0];
    int ps = fl / Kn, pe = fl % Kn;
    if (s0 == 0 && e0 == 0) { ps = 0; pe = 0; }
    ps_arr[b] = ps; pe_arr[b] = pe;
  }
}

// ---- per-batch logit losses: QA CE + consistency KL + span CE; 1 wave/batch ----
__global__ __launch_bounds__(64) void logit_losses_k(
    const float* __restrict__ wsl, const int* __restrict__ enst,
    const int* __restrict__ enen, const int* __restrict__ ps_arr,
    const int* __restrict__ pe_arr, float* __restrict__ acc) {
  int b = blockIdx.x;
  int lane = threadIdx.x;
  const float* es = wsl + (size_t)b * Kn;
  const float* ee = wsl + (size_t)BK + (size_t)b * Kn;
  const float* vs = wsl + (size_t)2 * BK + (size_t)b * Kn;
  const float* ve = wsl + (size_t)3 * BK + (size_t)b * Kn;
  float xes[3], xee[3], xvs[3], xve[3];
  #pragma unroll
  for (int j = 0; j < 3; ++j) {
    int idx = lane + 64 * j;
    bool val = idx < Kn;
    xes[j] = val ? es[idx] : -1e30f;
    xee[j] = val ? ee[idx] : -1e30f;
    xvs[j] = val ? vs[idx] : -1e30f;
    xve[j] = val ? ve[idx] : -1e30f;
  }
  auto wlse = [&](float x0, float x1, float x2) -> float {
    float m = fmaxf(fmaxf(x0, x1), x2);
    #pragma unroll
    for (int o = 32; o; o >>= 1) m = fmaxf(m, __shfl_xor(m, o));
    float s = expf(x0 - m) + expf(x1 - m) + expf(x2 - m);
    #pragma unroll
    for (int o = 32; o; o >>= 1) s += __shfl_xor(s, o);
    return m + logf(s);
  };
  float l_es = wlse(xes[0], xes[1], xes[2]);
  float l_ee = wlse(xee[0], xee[1], xee[2]);
  float l_vs = wlse(xvs[0], xvs[1], xvs[2]);
  float l_ve = wlse(xve[0], xve[1], xve[2]);
  float lT_es = wlse(xes[0]*0.5f, xes[1]*0.5f, xes[2]*0.5f);
  float lT_ee = wlse(xee[0]*0.5f, xee[1]*0.5f, xee[2]*0.5f);
  float lT_vs = wlse(xvs[0]*0.5f, xvs[1]*0.5f, xvs[2]*0.5f);
  float lT_ve = wlse(xve[0]*0.5f, xve[1]*0.5f, xve[2]*0.5f);
  float kls = 0.f, kle = 0.f;
  #pragma unroll
  for (int j = 0; j < 3; ++j) {
    int idx = lane + 64 * j;
    if (idx < Kn) {
      float aa = xes[j]*0.5f - lT_es;
      float bb = xvs[j]*0.5f - lT_vs;
      kls += expf(aa) * (aa - bb);
      float cc = xee[j]*0.5f - lT_ee;
      float dd = xve[j]*0.5f - lT_ve;
      kle += expf(cc) * (cc - dd);
    }
  }
  #pragma unroll
  for (int o = 32; o; o >>= 1) { kls += __shfl_xor(kls, o); kle += __shfl_xor(kle, o); }
  if (lane == 0) {
    int sl = min(max(enst[b], 0), Kn - 1);
    int el = min(max(enen[b], 0), Kn - 1);
    atomicAdd(acc + 0, l_es - es[sl]);
    atomicAdd(acc + 1, l_ee - ee[el]);
    atomicAdd(acc + 2, kls);
    atomicAdd(acc + 3, kle);
    int ps = ps_arr[b], pe = pe_arr[b];
    bool answerable = (enst[b] > 0) || (enen[b] > 0);
    if (answerable) {
      float ce = 0.5f * ((l_vs - vs[ps]) + (l_ve - ve[pe]));
      atomicAdd(acc + 8, ce);
      atomicAdd(acc + 9, 1.f);
    }
  }
}

// ---- MFMA FGW: gw3 = sum (D_en@g) o (g@D_vi) via Y@X^T swap-trick.
// 2 blocks per batch (tj column halves): h0 -> tj 0..2 (cols 0..95),
// h1 -> tj 3..4 (cols 96..159). Accumulators drop to 2 tiles/wave (64 regs)
// so 4 waves/SIMD stay resident. Siblings placed 8 apart (same XCD slot).
__global__ __launch_bounds__(512, 4) void fgw_k(
    const float* __restrict__ Den, const float* __restrict__ Dvi,
    const float* __restrict__ gam, const float* __restrict__ p_arr,
    const float* __restrict__ q_arr, float* __restrict__ acc) {
  __shared__ __align__(16) __bf16 sDen[2][2][Kn][8];  // D_en rows (full)
  __shared__ __align__(16) __bf16 sG  [2][2][Kn][8];  // gamma rows (full)
  __shared__ __align__(16) __bf16 sGT [2][2][96][8];  // gamma^T rows (tj half)
  __shared__ __align__(16) __bf16 sVT [2][2][96][8];  // D_vi^T rows (tj half)
  __shared__ float pq[2 * Kn];
  __shared__ float red[24];
  int bid = blockIdx.x;
  int h = (bid >> 3) & 1;
  int b = ((bid >> 4) << 3) | (bid & 7);
  const int JB = h ? 96 : 0;
  const int NBJ = h ? 64 : 96;
  const int NTJ = h ? 2 : 3;
  const int NT = 5 * NTJ;
  int tid = threadIdx.x;
  int wid = tid >> 6, lane = tid & 63;
  const float* den_b = Den + (size_t)b * Kn * Kn;
  const float* dvi_b = Dvi + (size_t)b * Kn * Kn;
  const float* gam_b = gam + (size_t)b * Kn * Kn;
  if (tid < 2 * Kn)
    pq[tid] = (tid < Kn) ? p_arr[(size_t)b * Kn + tid]
                         : q_arr[(size_t)b * Kn + (tid - Kn)];
  __syncthreads();
  float gw1 = 0.f, gw2 = 0.f;
  const int totalF = 640 + 4 * NBJ;  // 1024 (h0) / 896 (h1)

  auto stage = [&](int p, int db) {
    int k0 = p * KP;
    #pragma unroll
    for (int it = 0; it < 2; ++it) {
      int tau = tid + it * 512;
      if (tau < totalF) {
        float v[8];
        bf16x8 w;
        if (tau < 640) {  // row-major: sDen (0..320), sG (320..640)
          int op = tau >= 320;
          int f = tau - 320 * op;
          int c = f >= Kn;
          int r = f - Kn * c;
          int kb = k0 + 8 * c;
          const float* src = (op ? gam_b : den_b) + (size_t)r * Kn + kb;
          #pragma unroll
          for (int e2 = 0; e2 < 8; ++e2) v[e2] = src[e2];
          if (!op && h == 0) {
            float pi = pq[r];
            #pragma unroll
            for (int e2 = 0; e2 < 8; ++e2) gw1 += v[e2] * v[e2] * pi * pq[kb + e2];
          }
          #pragma unroll
          for (int e2 = 0; e2 < 8; ++e2) w[e2] = (__bf16)v[e2];
          if (op) *(bf16x8*)&sG[db][c][r][0] = w;
          else    *(bf16x8*)&sDen[db][c][r][0] = w;
        } else {          // transposed: sGT, sVT (tj half only)
          int f2 = tau - 640;
          int op = f2 >= 2 * NBJ;
          int f = f2 - 2 * NBJ * op;
          int c = f >= NBJ;
          int r = f - NBJ * c;
          int kb = k0 + 8 * c;
          int j = JB + r;
          const float* base = (op ? dvi_b : gam_b) + (size_t)kb * Kn + j;
          #pragma unroll
          for (int e2 = 0; e2 < 8; ++e2) v[e2] = base[(size_t)e2 * Kn];
          if (op) {
            float qj = pq[Kn + j];
            #pragma unroll
            for (int e2 = 0; e2 < 8; ++e2) gw2 += v[e2] * v[e2] * pq[Kn + kb + e2] * qj;
          }
          #pragma unroll
          for (int e2 = 0; e2 < 8; ++e2) w[e2] = (__bf16)v[e2];
          if (op) *(bf16x8*)&sVT[db][c][r][0] = w;
          else    *(bf16x8*)&sGT[db][c][r][0] = w;
        }
      }
    }
  };

  f32x16 acc1[2] = {};
  f32x16 acc2[2] = {};
  stage(0, 0);
  __syncthreads();
  int ra = lane & 31;
  int cc = lane >> 5;
  for (int p = 0; p < NP; ++p) {
    int cur = p & 1;
    if (p < NP - 1) stage(p + 1, cur ^ 1);
    #pragma unroll
    for (int n = 0; n < 2; ++n) {
      int t = wid + n * 8;
      if (t < NT) {
        int ti = t / NTJ, tjl = t - ti * NTJ;
        int rowa = ti * 32 + ra;
        int rowbl = tjl * 32 + ra;
        bf16x8 a1 = *(const bf16x8*)&sDen[cur][cc][rowa][0];
        bf16x8 b1 = *(const bf16x8*)&sGT[cur][cc][rowbl][0];
        bf16x8 a2 = *(const bf16x8*)&sG[cur][cc][rowa][0];
        bf16x8 b2 = *(const bf16x8*)&sVT[cur][cc][rowbl][0];
        acc1[n] = __builtin_amdgcn_mfma_f32_32x32x16_bf16(a1, b1, acc1[n], 0, 0, 0);
        acc2[n] = __builtin_amdgcn_mfma_f32_32x32x16_bf16(a2, b2, acc2[n], 0, 0, 0);
      }
    }
    __syncthreads();
  }
  float g3 = 0.f;
  #pragma unroll
  for (int n = 0; n < 2; ++n) {
    int t = wid + n * 8;
    if (t < NT) {
      #pragma unroll
      for (int r = 0; r < 16; ++r) g3 += acc1[n][r] * acc2[n][r];
    }
  }
  #pragma unroll
  for (int o = 32; o; o >>= 1) {
    gw1 += __shfl_xor(gw1, o);
    gw2 += __shfl_xor(gw2, o);
    g3 += __shfl_xor(g3, o);
  }
  if (lane == 0) { red[wid] = gw1; red[8 + wid] = gw2; red[16 + wid] = g3; }
  __syncthreads();
  if (tid == 0) {
    float s1 = 0.f, s2 = 0.f, s3 = 0.f;
    #pragma unroll
    for (int i = 0; i < 8; ++i) { s1 += red[i]; s2 += red[8 + i]; s3 += red[16 + i]; }
    if (h == 0) atomicAdd(acc + 5, s1);
    atomicAdd(acc + 6, s2);
    atomicAdd(acc + 7, s3);
  }
}

__global__ void finalize_k(const float* __restrict__ acc, float* __restrict__ out) {
  if (threadIdx.x == 0) {
    float ce_s = acc[0], ce_e = acc[1], kls = acc[2], kle = acc[3];
    float w = acc[4], gw1 = acc[5], gw2 = acc[6], gw3 = acc[7];
    float spn = acc[8], nans = acc[9];
    float l_qa = (ce_s + ce_e) / (2.f * Bn);
    float l_fgw = (ALPHA * (gw1 + gw2 - 2.f * gw3) + (1.f - ALPHA) * w) / Bn;
    float l_span = (nans > 0.f) ? spn / fmaxf(nans, 1.f) : 0.f;
    float l_cons = 2.f * (kls + kle) / Bn;  // T^2 * ((kls+kle)/B) / 2 with T=2
    float total = l_qa + L_FGW * l_fgw + L_SPAN * l_span + L_CONS * l_cons;
    out[0] = total; out[1] = l_qa; out[2] = l_fgw; out[3] = l_span; out[4] = l_cons;
  }
}

extern "C" void kernel_launch(void* const* d_in, const int* in_sizes, int n_in,
                              void* d_out, int out_size, void* d_ws, size_t ws_size,
                              hipStream_t stream) {
  const float* en  = (const float*)d_in[0];
  const float* vi  = (const float*)d_in[1];
  const float* gam = (const float*)d_in[2];
  const float* Den = (const float*)d_in[3];
  const float* Dvi = (const float*)d_in[4];
  const float* M   = (const float*)d_in[5];
  const int* enst  = (const int*)d_in[6];
  const int* enen  = (const int*)d_in[7];
  const float* w_s = (const float*)d_in[8];
  const float* b_s = (const float*)d_in[9];
  const float* w_e = (const float*)d_in[10];
  const float* b_e = (const float*)d_in[11];
  float* ws = (float*)d_ws;
  float* wsl = ws;                         // 4*BK logits: en_sl, en_el, vi_sl, vi_el
  float* p_arr = ws + (size_t)4 * BK;      // BK
  float* q_arr = p_arr + BK;               // BK
  int* ps_arr = (int*)(q_arr + BK);        // B
  int* pe_arr = ps_arr + Bn;               // B
  float* acc = (float*)(pe_arr + Bn);      // 16 accumulators
  float* out = (float*)d_out;

  qa_logits_k<<<(2 * BK) / 4, 256, 0, stream>>>(en, vi, w_s, b_s, w_e, b_e, wsl, acc);
  stats_span_k<<<Bn, 256, 0, stream>>>(gam, M, enst, enen, p_arr, q_arr, ps_arr, pe_arr, acc);
  logit_losses_k<<<Bn, 64, 0, stream>>>(wsl, enst, enen, ps_arr, pe_arr, acc);
  fgw_k<<<2 * Bn, 512, 0, stream>>>(Den, Dvi, gam, p_arr, q_arr, acc);
  finalize_k<<<1, 64, 0, stream>>>(acc, out);
}

// Round 4
// 197.210 us; speedup vs baseline: 2.2347x; 1.1483x over previous
//
#include <hip/hip_runtime.h>

#define Bn 512
#define Kn 160
#define Hn 256
#define BK (Bn*Kn)
#define ALPHA 0.5f
#define MAX_SPAN 30
#define L_FGW 0.1f
#define L_SPAN 0.5f
#define L_CONS 0.3f
#define KP 16
#define NP 10

typedef __bf16 bf16x8 __attribute__((ext_vector_type(8)));
typedef float f32x16 __attribute__((ext_vector_type(16)));

// raw barrier: LDS drained, global loads stay in flight (no vmcnt drain)
__device__ __forceinline__ void wg_barrier() {
  asm volatile("s_waitcnt lgkmcnt(0)" ::: "memory");
  __builtin_amdgcn_s_barrier();
  __builtin_amdgcn_sched_barrier(0);
}

// ---- QA head logits: one wave per (emb,row); H=256 = 64 lanes x float4 ----
__global__ __launch_bounds__(256) void qa_logits_k(
    const float* __restrict__ en, const float* __restrict__ vi,
    const float* __restrict__ w_s, const float* __restrict__ b_s,
    const float* __restrict__ w_e, const float* __restrict__ b_e,
    float* __restrict__ wsl, float* __restrict__ acc) {
  if (blockIdx.x == 0 && threadIdx.x < 16) acc[threadIdx.x] = 0.f;
  int row = blockIdx.x * 4 + (threadIdx.x >> 6);
  int lane = threadIdx.x & 63;
  bool isVi = row >= BK;
  int r = isVi ? row - BK : row;
  const float* emb = isVi ? vi : en;
  float4 v = *(const float4*)(emb + (size_t)r * Hn + lane * 4);
  float4 a = *(const float4*)(w_s + lane * 4);
  float4 c = *(const float4*)(w_e + lane * 4);
  float ds = v.x*a.x + v.y*a.y + v.z*a.z + v.w*a.w;
  float de = v.x*c.x + v.y*c.y + v.z*c.z + v.w*c.w;
  #pragma unroll
  for (int o = 32; o; o >>= 1) { ds += __shfl_xor(ds, o); de += __shfl_xor(de, o); }
  if (lane == 0) {
    size_t base = isVi ? (size_t)2 * BK : 0;
    wsl[base + r] = ds + b_s[0];
    wsl[base + BK + r] = de + b_e[0];
  }
}

// ---- fused: gamma stats (p,q,w) + span decode + QA CE + KL + span CE ----
__global__ __launch_bounds__(512) void stats_logit_k(
    const float* __restrict__ gam, const float* __restrict__ M,
    const int* __restrict__ enst, const int* __restrict__ enen,
    const float* __restrict__ wsl, float* __restrict__ p_arr,
    float* __restrict__ q_arr, float* __restrict__ acc) {
  __shared__ float qsh[Kn];
  __shared__ float vsc[Kn];
  __shared__ float wsh[8];
  __shared__ float bv[512];
  __shared__ int bidx[512];
  __shared__ int pspe[2];
  int b = blockIdx.x, tid = threadIdx.x;
  int wid = tid >> 6, lane = tid & 63;
  for (int t = tid; t < Kn; t += 512) { qsh[t] = 0.f; vsc[t] = 0.f; }
  __syncthreads();
  int s0 = enst[b], e0 = enen[b];
  int s = min(max(s0, 0), Kn - 1);
  int e = max(s, min(max(e0, 0), Kn - 1));
  const float* gb = gam + (size_t)b * Kn * Kn;
  const float* mb = M + (size_t)b * Kn * Kn;
  bool tail = lane < 16;
  float qx = 0.f, qy = 0.f, qz = 0.f, qw = 0.f;
  float vx = 0.f, vy = 0.f, vz = 0.f, vw = 0.f;
  float wloc = 0.f;
  for (int i = wid; i < Kn; i += 8) {
    const float2* g2 = (const float2*)(gb + (size_t)i * Kn);
    const float2* m2 = (const float2*)(mb + (size_t)i * Kn);
    float2 gA = g2[lane];
    float2 mA = m2[lane];
    float2 gB = {0.f, 0.f}, mB = {0.f, 0.f};
    if (tail) { gB = g2[64 + lane]; mB = m2[64 + lane]; }
    qx += gA.x; qy += gA.y; qz += gB.x; qw += gB.y;
    wloc += mA.x * gA.x + mA.y * gA.y + mB.x * gB.x + mB.y * gB.y;
    float rs = gA.x + gA.y + gB.x + gB.y;
    #pragma unroll
    for (int o = 32; o; o >>= 1) rs += __shfl_xor(rs, o);
    if (lane == 0) p_arr[(size_t)b * Kn + i] = rs;
    float f = (i >= s && i <= e) ? 1.f : 0.f;
    vx += f * gA.x; vy += f * gA.y; vz += f * gB.x; vw += f * gB.y;
  }
  atomicAdd(&qsh[2 * lane], qx); atomicAdd(&qsh[2 * lane + 1], qy);
  atomicAdd(&vsc[2 * lane], vx); atomicAdd(&vsc[2 * lane + 1], vy);
  if (tail) {
    atomicAdd(&qsh[128 + 2 * lane], qz); atomicAdd(&qsh[128 + 2 * lane + 1], qw);
    atomicAdd(&vsc[128 + 2 * lane], vz); atomicAdd(&vsc[128 + 2 * lane + 1], vw);
  }
  #pragma unroll
  for (int o = 32; o; o >>= 1) wloc += __shfl_xor(wloc, o);
  if (lane == 0) wsh[wid] = wloc;
  __syncthreads();
  if (tid < Kn) q_arr[(size_t)b * Kn + tid] = qsh[tid];
  if (tid == 0) {
    float sw = 0.f;
    #pragma unroll
    for (int i2 = 0; i2 < 8; ++i2) sw += wsh[i2];
    atomicAdd(acc + 4, sw);
  }
  // ---- span argmax (first-max semantics) ----
  float best = -1e30f;
  int bfl = 0x7fffffff;
  if (tid < Kn) {
    float vsi = vsc[tid];
    int hi = min(tid + MAX_SPAN, Kn - 1);
    for (int ei = tid; ei <= hi; ++ei) {
      float v = vsi + vsc[ei];
      if (v > best) { best = v; bfl = tid * Kn + ei; }
    }
  }
  bv[tid] = best; bidx[tid] = bfl;
  for (int st = 256; st > 0; st >>= 1) {
    __syncthreads();
    if (tid < st) {
      float v2 = bv[tid + st]; int i2 = bidx[tid + st];
      if (v2 > bv[tid] || (v2 == bv[tid] && i2 < bidx[tid])) { bv[tid] = v2; bidx[tid] = i2; }
    }
  }
  if (tid == 0) {
    int fl = bidx[0];
    int ps = fl / Kn, pe = fl - (fl / Kn) * Kn;
    if (s0 == 0 && e0 == 0) { ps = 0; pe = 0; }
    pspe[0] = ps; pspe[1] = pe;
  }
  __syncthreads();
  // ---- logit losses: wave 0 only ----
  if (wid == 0) {
    const float* es = wsl + (size_t)b * Kn;
    const float* ee = wsl + (size_t)BK + (size_t)b * Kn;
    const float* vs = wsl + (size_t)2 * BK + (size_t)b * Kn;
    const float* ve = wsl + (size_t)3 * BK + (size_t)b * Kn;
    float xes[3], xee[3], xvs[3], xve[3];
    #pragma unroll
    for (int j = 0; j < 3; ++j) {
      int idx = lane + 64 * j;
      bool val = idx < Kn;
      xes[j] = val ? es[idx] : -1e30f;
      xee[j] = val ? ee[idx] : -1e30f;
      xvs[j] = val ? vs[idx] : -1e30f;
      xve[j] = val ? ve[idx] : -1e30f;
    }
    auto wlse = [&](float x0, float x1, float x2) -> float {
      float m = fmaxf(fmaxf(x0, x1), x2);
      #pragma unroll
      for (int o = 32; o; o >>= 1) m = fmaxf(m, __shfl_xor(m, o));
      float su = expf(x0 - m) + expf(x1 - m) + expf(x2 - m);
      #pragma unroll
      for (int o = 32; o; o >>= 1) su += __shfl_xor(su, o);
      return m + logf(su);
    };
    float l_es = wlse(xes[0], xes[1], xes[2]);
    float l_ee = wlse(xee[0], xee[1], xee[2]);
    float l_vs = wlse(xvs[0], xvs[1], xvs[2]);
    float l_ve = wlse(xve[0], xve[1], xve[2]);
    float lT_es = wlse(xes[0]*0.5f, xes[1]*0.5f, xes[2]*0.5f);
    float lT_ee = wlse(xee[0]*0.5f, xee[1]*0.5f, xee[2]*0.5f);
    float lT_vs = wlse(xvs[0]*0.5f, xvs[1]*0.5f, xvs[2]*0.5f);
    float lT_ve = wlse(xve[0]*0.5f, xve[1]*0.5f, xve[2]*0.5f);
    float kls = 0.f, kle = 0.f;
    #pragma unroll
    for (int j = 0; j < 3; ++j) {
      int idx = lane + 64 * j;
      if (idx < Kn) {
        float aa = xes[j]*0.5f - lT_es;
        float bb = xvs[j]*0.5f - lT_vs;
        kls += expf(aa) * (aa - bb);
        float cc = xee[j]*0.5f - lT_ee;
        float dd = xve[j]*0.5f - lT_ve;
        kle += expf(cc) * (cc - dd);
      }
    }
    #pragma unroll
    for (int o = 32; o; o >>= 1) { kls += __shfl_xor(kls, o); kle += __shfl_xor(kle, o); }
    if (lane == 0) {
      int sl = min(max(s0, 0), Kn - 1);
      int el = min(max(e0, 0), Kn - 1);
      atomicAdd(acc + 0, l_es - es[sl]);
      atomicAdd(acc + 1, l_ee - ee[el]);
      atomicAdd(acc + 2, kls);
      atomicAdd(acc + 3, kle);
      if (s0 > 0 || e0 > 0) {
        float ce = 0.5f * ((l_vs - vs[pspe[0]]) + (l_ve - ve[pspe[1]]));
        atomicAdd(acc + 8, ce);
        atomicAdd(acc + 9, 1.f);
      }
    }
  }
}

// ---- MFMA FGW, software-pipelined: loads for panel p+2 issued in phase p,
// ds_write in phase p+1, raw s_barrier (lgkm-only drain) so global loads
// stay in flight across barriers. 2 blocks/batch (column halves).
__global__ __launch_bounds__(512, 3) void fgw_k(
    const float* __restrict__ Den, const float* __restrict__ Dvi,
    const float* __restrict__ gam, const float* __restrict__ p_arr,
    const float* __restrict__ q_arr, float* __restrict__ acc) {
  __shared__ __align__(16) __bf16 sDen[2][2][Kn][8];
  __shared__ __align__(16) __bf16 sG  [2][2][Kn][8];
  __shared__ __align__(16) __bf16 sGT [2][2][96][8];
  __shared__ __align__(16) __bf16 sVT [2][2][96][8];
  __shared__ float pq[2 * Kn];
  __shared__ float red[24];
  int bid = blockIdx.x;
  int h = (bid >> 3) & 1;
  int b = ((bid >> 4) << 3) | (bid & 7);
  const int JB = h ? 96 : 0;
  const int NBJ = h ? 64 : 96;
  const int NTJ = h ? 2 : 3;
  const int NT = 5 * NTJ;
  int tid = threadIdx.x;
  int wid = tid >> 6, lane = tid & 63;
  const float* den_b = Den + (size_t)b * Kn * Kn;
  const float* dvi_b = Dvi + (size_t)b * Kn * Kn;
  const float* gam_b = gam + (size_t)b * Kn * Kn;
  if (tid < 2 * Kn)
    pq[tid] = (tid < Kn) ? p_arr[(size_t)b * Kn + tid]
                         : q_arr[(size_t)b * Kn + (tid - Kn)];
  __syncthreads();

  // ---- per-thread fragment decode (fixed geometry) ----
  // slot0 (tau=tid, 0..511): always row-major. tau<320 -> sDen, else sG.
  int op0 = tid >= 320 ? 1 : 0;
  int f0 = tid - 320 * op0;
  int c0 = f0 >= Kn ? 1 : 0;
  int r0 = f0 - Kn * c0;
  const float* s0p = (op0 ? gam_b : den_b) + (size_t)r0 * Kn + 8 * c0;
  __bf16* d00 = op0 ? &sG[0][c0][r0][0] : &sDen[0][c0][r0][0];
  __bf16* d01 = op0 ? &sG[1][c0][r0][0] : &sDen[1][c0][r0][0];
  int gw1k = (!op0 && h == 0) ? 1 : 0;
  float wgt0 = gw1k ? pq[r0] : 0.f;
  const float* pqb0 = pq + 8 * c0;
  // slot1 (tau=tid+512): tid<128 -> row-major (sG,c=1,r=tid+32); else transposed.
  bool rm1 = tid < 128;
  bool act1 = (tid + 512) < (640 + 4 * NBJ);
  const float* s1p = den_b;  // dummy init
  __bf16* d10 = &sGT[0][0][0][0];
  __bf16* d11 = &sGT[1][0][0][0];
  int gw2k = 0;
  float wgt1 = 0.f;
  const float* pqb1 = pq;
  if (act1) {
    if (rm1) {
      int r1 = tid + 32;
      s1p = gam_b + (size_t)r1 * Kn + 8;
      d10 = &sG[0][1][r1][0];
      d11 = &sG[1][1][r1][0];
    } else {
      int f2 = tid - 128;
      int op1 = f2 >= 2 * NBJ ? 1 : 0;
      int f = f2 - 2 * NBJ * op1;
      int c1 = f >= NBJ ? 1 : 0;
      int r1 = f - NBJ * c1;
      int j = JB + r1;
      s1p = (op1 ? dvi_b : gam_b) + (size_t)(8 * c1) * Kn + j;
      d10 = op1 ? &sVT[0][c1][r1][0] : &sGT[0][c1][r1][0];
      d11 = op1 ? &sVT[1][c1][r1][0] : &sGT[1][c1][r1][0];
      if (op1) { gw2k = 1; wgt1 = pq[Kn + j]; pqb1 = pq + Kn + 8 * c1; }
    }
  }
  float gw1a = 0.f, gw2a = 0.f;
  float vA0[8], vA1[8], vB0[8], vB1[8];

  auto load0 = [&](int p, float* v) {
    const float* sp = s0p + p * KP;
    float4 x = *(const float4*)sp;
    float4 y = *(const float4*)(sp + 4);
    v[0]=x.x; v[1]=x.y; v[2]=x.z; v[3]=x.w;
    v[4]=y.x; v[5]=y.y; v[6]=y.z; v[7]=y.w;
  };
  auto load1 = [&](int p, float* v) {
    if (!act1) return;
    if (rm1) {
      const float* sp = s1p + p * KP;
      float4 x = *(const float4*)sp;
      float4 y = *(const float4*)(sp + 4);
      v[0]=x.x; v[1]=x.y; v[2]=x.z; v[3]=x.w;
      v[4]=y.x; v[5]=y.y; v[6]=y.z; v[7]=y.w;
    } else {
      const float* sp = s1p + (size_t)p * KP * Kn;
      #pragma unroll
      for (int e2 = 0; e2 < 8; ++e2) v[e2] = sp[(size_t)e2 * Kn];
    }
  };
  auto wr = [&](int p, const float* v0, const float* v1, __bf16* w0, __bf16* w1) {
    if (gw1k) {
      const float* pp = pqb0 + p * KP;
      float g = 0.f;
      #pragma unroll
      for (int e2 = 0; e2 < 8; ++e2) g += v0[e2] * v0[e2] * pp[e2];
      gw1a += g * wgt0;
    }
    bf16x8 wv;
    #pragma unroll
    for (int e2 = 0; e2 < 8; ++e2) wv[e2] = (__bf16)v0[e2];
    *(bf16x8*)w0 = wv;
    if (act1) {
      if (gw2k) {
        const float* pp = pqb1 + p * KP;
        float g = 0.f;
        #pragma unroll
        for (int e2 = 0; e2 < 8; ++e2) g += v1[e2] * v1[e2] * pp[e2];
        gw2a += g * wgt1;
      }
      bf16x8 wv2;
      #pragma unroll
      for (int e2 = 0; e2 < 8; ++e2) wv2[e2] = (__bf16)v1[e2];
      *(bf16x8*)w1 = wv2;
    }
  };

  // ---- MFMA tile geometry (fixed per wave) ----
  int ra = lane & 31, cc2 = lane >> 5;
  int t1i = wid + 8;
  bool val1t = t1i < NT;
  int ti0 = wid / NTJ, tj0 = wid - ti0 * NTJ;
  int rowa0 = ti0 * 32 + ra, rowb0 = tj0 * 32 + ra;
  int ti1 = t1i / NTJ, tj1 = t1i - ti1 * NTJ;
  int rowa1 = ti1 * 32 + ra, rowb1 = tj1 * 32 + ra;
  f32x16 acc10 = {}, acc20 = {}, acc11 = {}, acc21 = {};
  auto mf = [&](int BUF) {
    {
      bf16x8 a1 = *(const bf16x8*)&sDen[BUF][cc2][rowa0][0];
      bf16x8 b1 = *(const bf16x8*)&sGT[BUF][cc2][rowb0][0];
      bf16x8 a2 = *(const bf16x8*)&sG[BUF][cc2][rowa0][0];
      bf16x8 b2 = *(const bf16x8*)&sVT[BUF][cc2][rowb0][0];
      acc10 = __builtin_amdgcn_mfma_f32_32x32x16_bf16(a1, b1, acc10, 0, 0, 0);
      acc20 = __builtin_amdgcn_mfma_f32_32x32x16_bf16(a2, b2, acc20, 0, 0, 0);
    }
    if (val1t) {
      bf16x8 a1 = *(const bf16x8*)&sDen[BUF][cc2][rowa1][0];
      bf16x8 b1 = *(const bf16x8*)&sGT[BUF][cc2][rowb1][0];
      bf16x8 a2 = *(const bf16x8*)&sG[BUF][cc2][rowa1][0];
      bf16x8 b2 = *(const bf16x8*)&sVT[BUF][cc2][rowb1][0];
      acc11 = __builtin_amdgcn_mfma_f32_32x32x16_bf16(a1, b1, acc11, 0, 0, 0);
      acc21 = __builtin_amdgcn_mfma_f32_32x32x16_bf16(a2, b2, acc21, 0, 0, 0);
    }
  };

  // ---- pipelined main loop ----
  load0(0, vA0); load1(0, vA1);
  load0(1, vB0); load1(1, vB1);
  wr(0, vA0, vA1, d00, d10);
  __syncthreads();
  for (int p = 0; p < NP; p += 2) {
    if (p + 2 < NP) { load0(p + 2, vA0); load1(p + 2, vA1); }
    mf(0);
    wr(p + 1, vB0, vB1, d01, d11);
    wg_barrier();
    if (p + 3 < NP) { load0(p + 3, vB0); load1(p + 3, vB1); }
    mf(1);
    if (p + 2 < NP) wr(p + 2, vA0, vA1, d00, d10);
    wg_barrier();
  }
  // ---- reduce ----
  float g3 = 0.f;
  #pragma unroll
  for (int r2 = 0; r2 < 16; ++r2) g3 += acc10[r2] * acc20[r2];
  if (val1t) {
    #pragma unroll
    for (int r2 = 0; r2 < 16; ++r2) g3 += acc11[r2] * acc21[r2];
  }
  #pragma unroll
  for (int o = 32; o; o >>= 1) {
    gw1a += __shfl_xor(gw1a, o);
    gw2a += __shfl_xor(gw2a, o);
    g3 += __shfl_xor(g3, o);
  }
  if (lane == 0) { red[wid] = gw1a; red[8 + wid] = gw2a; red[16 + wid] = g3; }
  __syncthreads();
  if (tid == 0) {
    float s1 = 0.f, s2 = 0.f, s3 = 0.f;
    #pragma unroll
    for (int i = 0; i < 8; ++i) { s1 += red[i]; s2 += red[8 + i]; s3 += red[16 + i]; }
    if (h == 0) atomicAdd(acc + 5, s1);
    atomicAdd(acc + 6, s2);
    atomicAdd(acc + 7, s3);
  }
}

__global__ void finalize_k(const float* __restrict__ acc, float* __restrict__ out) {
  if (threadIdx.x == 0) {
    float ce_s = acc[0], ce_e = acc[1], kls = acc[2], kle = acc[3];
    float w = acc[4], gw1 = acc[5], gw2 = acc[6], gw3 = acc[7];
    float spn = acc[8], nans = acc[9];
    float l_qa = (ce_s + ce_e) / (2.f * Bn);
    float l_fgw = (ALPHA * (gw1 + gw2 - 2.f * gw3) + (1.f - ALPHA) * w) / Bn;
    float l_span = (nans > 0.f) ? spn / fmaxf(nans, 1.f) : 0.f;
    float l_cons = 2.f * (kls + kle) / Bn;  // T^2 * ((kls+kle)/B) / 2 with T=2
    float total = l_qa + L_FGW * l_fgw + L_SPAN * l_span + L_CONS * l_cons;
    out[0] = total; out[1] = l_qa; out[2] = l_fgw; out[3] = l_span; out[4] = l_cons;
  }
}

extern "C" void kernel_launch(void* const* d_in, const int* in_sizes, int n_in,
                              void* d_out, int out_size, void* d_ws, size_t ws_size,
                              hipStream_t stream) {
  const float* en  = (const float*)d_in[0];
  const float* vi  = (const float*)d_in[1];
  const float* gam = (const float*)d_in[2];
  const float* Den = (const float*)d_in[3];
  const float* Dvi = (const float*)d_in[4];
  const float* M   = (const float*)d_in[5];
  const int* enst  = (const int*)d_in[6];
  const int* enen  = (const int*)d_in[7];
  const float* w_s = (const float*)d_in[8];
  const float* b_s = (const float*)d_in[9];
  const float* w_e = (const float*)d_in[10];
  const float* b_e = (const float*)d_in[11];
  float* ws = (float*)d_ws;
  float* wsl = ws;                         // 4*BK logits
  float* p_arr = ws + (size_t)4 * BK;      // BK
  float* q_arr = p_arr + BK;               // BK
  float* acc = q_arr + BK;                 // 16 accumulators
  float* out = (float*)d_out;

  qa_logits_k<<<(2 * BK) / 4, 256, 0, stream>>>(en, vi, w_s, b_s, w_e, b_e, wsl, acc);
  stats_logit_k<<<Bn, 512, 0, stream>>>(gam, M, enst, enen, wsl, p_arr, q_arr, acc);
  fgw_k<<<2 * Bn, 512, 0, stream>>>(Den, Dvi, gam, p_arr, q_arr, acc);
  finalize_k<<<1, 64, 0, stream>>>(acc, out);
}